// Round 21
// baseline (189.823 us; speedup 1.0000x reference)
//
#include <hip/hip_runtime.h>
#include <hip/hip_bf16.h>

// DeepViT re-attention — fused S-in-LDS pipeline, v6 (phase-decoupled kFused).
//  k1 gemm_qkv: qkv = x @ w_qkv^T, BM=64 (768 blocks), f32 stage-convert,
//               XCD swizzle, fused innerF zeroing
//  k2 passA   : softmax stats (m, l), j-split x8 (4096 blocks), XCD swizzle
//  k3 kFused  : 256-thr blocks (i-tile 32, wave = heads {w, w+4}), LDS 69.5KB
//               -> 2 INDEPENDENT blocks/CU: block A's mix (VALU) overlaps
//               block B's QK^T/PV (MFMA) — replaces intra-wave prefetch.
//               Spk stride 520 kills the 8-way mix-read bank conflict.
//               grid (64,2,4) natural order: jq-contending blocks differ by
//               128 in id -> same XCD -> atomic lines stay in one L2 (R19/R20).
//  k4 gemm_out: out = innerF(f32 staged) @ w_out^T + b_out, BM=64 (256 blocks)

typedef __attribute__((ext_vector_type(8))) short bfx8;
typedef __attribute__((ext_vector_type(4))) float f32x4;
typedef unsigned short u16;
typedef unsigned int u32;

#define QSCALE 0.18033688011112042f  /* (1/8) * log2(e) */
#define SPK_STRIDE 520               /* u16; 520*2/4 = 260 ≡ 4 (mod 32) -> i spreads banks */

static __device__ inline u16 f2bf(float f) {
  union { float f; unsigned u; } cv; cv.f = f;
  unsigned u = cv.u;
  u += 0x7fffu + ((u >> 16) & 1u);   // RNE
  return (u16)(u >> 16);
}
static __device__ inline u32 cvtpk(float lo, float hi) {  // {bf16(lo), bf16(hi)}
  u32 d; asm("v_cvt_pk_bf16_f32 %0, %1, %2" : "=v"(d) : "v"(lo), "v"(hi)); return d;
}
static __device__ inline float fexp2(float x) {
  float r; asm("v_exp_f32 %0, %1" : "=v"(r) : "v"(x)); return r;
}
static __device__ inline float flog2(float x) {
  float r; asm("v_log_f32 %0, %1" : "=v"(r) : "v"(x)); return r;
}
static __device__ inline uint4 pk8(const float* p) {  // 8 f32 -> 8 bf16 (uint4)
  float4 a = *(const float4*)p, b = *(const float4*)(p + 4);
  return make_uint4(cvtpk(a.x, a.y), cvtpk(a.z, a.w), cvtpk(b.x, b.y), cvtpk(b.z, b.w));
}

// ---------------- k1: GEMM C = x @ w_qkv^T, BM=64, fused innerF zero ----------------
__global__ __launch_bounds__(256) void gemm_qkv(
    const float* __restrict__ A, const float* __restrict__ B,
    u16* __restrict__ qb, u16* __restrict__ kb, u16* __restrict__ vtb,
    float4* __restrict__ zeroF) {
  __shared__ u16 As[64 * 32];
  __shared__ u16 Bs[128 * 32];
  const int bid = blockIdx.x, t = threadIdx.x;
  for (int e = bid * 256 + t; e < 524288; e += 196608)
    zeroF[e] = make_float4(0.f, 0.f, 0.f, 0.f);
  const int swzb = (bid & 7) * 96 + (bid >> 3);
  const int m0 = (swzb / 12) * 64, n0 = (swzb % 12) * 128;
  const int lane = t & 63, w = t >> 6;
  const int li = lane & 15, lg = lane >> 4;
  const int rowA = t >> 2, kb8 = (t & 3) * 8;
  f32x4 acc[4][2] = {};
  for (int k0 = 0; k0 < 512; k0 += 32) {
    __syncthreads();
    *(uint4*)&As[rowA * 32 + kb8]        = pk8(&A[(size_t)(m0 + rowA) * 512 + k0 + kb8]);
    *(uint4*)&Bs[rowA * 32 + kb8]        = pk8(&B[(size_t)(n0 + rowA) * 512 + k0 + kb8]);
    *(uint4*)&Bs[(rowA + 64) * 32 + kb8] = pk8(&B[(size_t)(n0 + rowA + 64) * 512 + k0 + kb8]);
    __syncthreads();
    bfx8 af[4], bf_[2];
#pragma unroll
    for (int mi = 0; mi < 4; mi++)
      af[mi] = *(const bfx8*)&As[(mi * 16 + li) * 32 + lg * 8];
#pragma unroll
    for (int ni = 0; ni < 2; ni++)
      bf_[ni] = *(const bfx8*)&Bs[(w * 32 + ni * 16 + li) * 32 + lg * 8];
#pragma unroll
    for (int mi = 0; mi < 4; mi++)
#pragma unroll
      for (int ni = 0; ni < 2; ni++)
        acc[mi][ni] = __builtin_amdgcn_mfma_f32_16x16x32_bf16(af[mi], bf_[ni], acc[mi][ni], 0, 0, 0);
  }
#pragma unroll
  for (int mi = 0; mi < 4; mi++) {
#pragma unroll
    for (int ni = 0; ni < 2; ni++) {
      const int nc  = n0 + w * 32 + ni * 16 + li;
      const int mrb = m0 + mi * 16 + lg * 4;
      const int part = nc >> 9, within = nc & 511;
      const int h = within >> 6, d = within & 63;
      const int bb = mrb >> 11, ii = mrb & 2047;
      if (part == 0) {
#pragma unroll
        for (int r = 0; r < 4; r++)
          qb[(((size_t)bb * 8 + h) * 2048 + ii + r) * 64 + d] = f2bf(acc[mi][ni][r] * QSCALE);
      } else if (part == 1) {
#pragma unroll
        for (int r = 0; r < 4; r++)
          kb[(((size_t)bb * 8 + h) * 2048 + ii + r) * 64 + d] = f2bf(acc[mi][ni][r]);
      } else {
        ushort4 u;
        u.x = f2bf(acc[mi][ni][0]); u.y = f2bf(acc[mi][ni][1]);
        u.z = f2bf(acc[mi][ni][2]); u.w = f2bf(acc[mi][ni][3]);
        *(ushort4*)&vtb[(((size_t)bb * 8 + h) * 64 + d) * 2048 + ii] = u;
      }
    }
  }
}

// ---------------- k2: softmax stats (m, l), j-split x8, XCD-swizzled ----------------
__global__ __launch_bounds__(256) void passA(
    const u16* __restrict__ qb, const u16* __restrict__ kb,
    float2* __restrict__ statp) {
  const int bid = blockIdx.x;
  const int swzb = (bid & 7) * 512 + (bid >> 3);
  const int bx = swzb & 31, bh = (swzb >> 5) & 15, js = swzb >> 9;  // js 0..7
  const int t = threadIdx.x, lane = t & 63, w = t >> 6;
  const int i0 = bx * 64 + w * 16;
  const int li = lane & 15, lg = lane >> 4;
  const u16* Qh = qb + ((size_t)bh * 2048 + i0 + li) * 64;
  const u16* Kb = kb + (size_t)bh * 2048 * 64;
  const bfx8 q0 = *(const bfx8*)&Qh[lg * 8];
  const bfx8 q1 = *(const bfx8*)&Qh[32 + lg * 8];
  float m = -1e30f, l = 0.f;
  const int jbeg = js * 256, jend = jbeg + 256;
  for (int j0 = jbeg; j0 < jend; j0 += 32) {
    const u16* KhA = Kb + (size_t)(j0 + li) * 64;
    const u16* KhB = KhA + 16 * 64;
    bfx8 a0 = *(const bfx8*)&KhA[lg * 8];
    bfx8 a1 = *(const bfx8*)&KhA[32 + lg * 8];
    bfx8 b0 = *(const bfx8*)&KhB[lg * 8];
    bfx8 b1 = *(const bfx8*)&KhB[32 + lg * 8];
    __builtin_amdgcn_sched_barrier(0);
    f32x4 sa = {0.f, 0.f, 0.f, 0.f}, sb = {0.f, 0.f, 0.f, 0.f};
    sa = __builtin_amdgcn_mfma_f32_16x16x32_bf16(a0, q0, sa, 0, 0, 0);
    sa = __builtin_amdgcn_mfma_f32_16x16x32_bf16(a1, q1, sa, 0, 0, 0);
    sb = __builtin_amdgcn_mfma_f32_16x16x32_bf16(b0, q0, sb, 0, 0, 0);
    sb = __builtin_amdgcn_mfma_f32_16x16x32_bf16(b1, q1, sb, 0, 0, 0);
    float mt = fmaxf(fmaxf(fmaxf(sa[0], sa[1]), fmaxf(sa[2], sa[3])),
                     fmaxf(fmaxf(sb[0], sb[1]), fmaxf(sb[2], sb[3])));
    float mn = fmaxf(m, mt);
    float es = (fexp2(sa[0] - mn) + fexp2(sa[1] - mn)) + (fexp2(sa[2] - mn) + fexp2(sa[3] - mn))
             + (fexp2(sb[0] - mn) + fexp2(sb[1] - mn)) + (fexp2(sb[2] - mn) + fexp2(sb[3] - mn));
    l = fmaf(l, fexp2(m - mn), es);
    m = mn;
  }
  for (int off = 16; off < 64; off <<= 1) {
    float mo = __shfl_xor(m, off, 64);
    float lo = __shfl_xor(l, off, 64);
    float mn = fmaxf(m, mo);
    l = l * fexp2(m - mn) + lo * fexp2(mo - mn);
    m = mn;
  }
  if (lane < 16) statp[(size_t)js * 32768 + (size_t)bh * 2048 + i0 + li] = make_float2(m, l);
}

// ---------------- k3: kFused — phase-decoupled 256-thr blocks ----------------
// grid (64 i-tiles of 32, 2 b, 4 jq), 256 thr = 4 waves; wave w = heads {w, w+4}.
__global__ __launch_bounds__(256) void kFused(
    const u16* __restrict__ qb, const u16* __restrict__ kb,
    const u16* __restrict__ vtb, const float2* __restrict__ statp,
    const float* __restrict__ Wmix, const float* __restrict__ lng,
    const float* __restrict__ lnb, float* __restrict__ innerF) {
  __shared__ __align__(16) u16 Spk[32 * SPK_STRIDE]; // 32.5KB p bf16 [i][h*64+x], padded stride
  __shared__ __align__(16) u16 A2h[8 * 32 * 72];     // 36KB  A'' bf16 [g][i][x]
  __shared__ float stMs[32 * 8];                     // 1KB   M [i][h]
  const int t = threadIdx.x, lane = t & 63, w = t >> 6;
  const int li = lane & 15, lg = lane >> 4;
  const int ig = blockIdx.x * 32, b = blockIdx.y, j0 = blockIdx.z * 512;

  float wm_[8][8], lng_[8], lnb_[8];   // uniform -> SGPR
#pragma unroll
  for (int h = 0; h < 8; h++)
#pragma unroll
    for (int g = 0; g < 8; g++) wm_[h][g] = Wmix[h * 8 + g];
#pragma unroll
  for (int g = 0; g < 8; g++) { lng_[g] = lng[g]; lnb_[g] = lnb[g]; }

  // stats merge over 8 j-split partials -> stMs[i][h] (256 entries, 1/thread)
  {
    const int i = t >> 3, h = t & 7;
    const size_t idx = ((size_t)(b * 8 + h)) * 2048 + ig + i;
    float m = -1e30f, l = 0.f;
#pragma unroll
    for (int z = 0; z < 8; z++) {
      const float2 a = statp[(size_t)z * 32768 + idx];
      const float mn = fmaxf(m, a.x);
      l = l * fexp2(m - mn) + a.y * fexp2(a.x - mn);
      m = mn;
    }
    stMs[i * 8 + h] = m + flog2(l);
  }

  // Q fragments for heads w, w+4 (held in regs; i-tile 32 -> ii 0..1)
  bfx8 qf[2][2][2];
#pragma unroll
  for (int hh = 0; hh < 2; hh++)
#pragma unroll
    for (int ii = 0; ii < 2; ii++)
#pragma unroll
      for (int ks = 0; ks < 2; ks++)
        qf[hh][ii][ks] = *(const bfx8*)&qb[(((size_t)(b * 8 + w + hh * 4)) * 2048
                                            + ig + ii * 16 + li) * 64 + ks * 32 + lg * 8];
  __syncthreads();
  float stMp[2][2];   // [hh][ii]
#pragma unroll
  for (int hh = 0; hh < 2; hh++)
#pragma unroll
    for (int ii = 0; ii < 2; ii++)
      stMp[hh][ii] = stMs[(ii * 16 + li) * 8 + w + hh * 4];

  f32x4 pacc[2][2][4] = {};   // [hh][iSub][dt] = 64 AGPR
  const int mixI = t >> 3, mixJ8 = (t & 7) * 8;
  const int mixSwz = (mixI & 7) << 3;

  for (int jt = j0; jt < j0 + 512; jt += 64) {
    // QK^T per head: load K, 16 MFMA, exp2+pack to Spk
#pragma unroll
    for (int hh = 0; hh < 2; hh++) {
      const int h = w + hh * 4;
      bfx8 kf[4][2];
#pragma unroll
      for (int ji = 0; ji < 4; ji++)
#pragma unroll
        for (int ks = 0; ks < 2; ks++)
          kf[ji][ks] = *(const bfx8*)&kb[(((size_t)(b * 8 + h)) * 2048 + jt + ji * 16 + li) * 64
                                         + ks * 32 + lg * 8];
      __builtin_amdgcn_sched_barrier(0);
#pragma unroll
      for (int ii = 0; ii < 2; ii++) {
        f32x4 s[4] = {};
#pragma unroll
        for (int ji = 0; ji < 4; ji++) {
          s[ji] = __builtin_amdgcn_mfma_f32_16x16x32_bf16(kf[ji][0], qf[hh][ii][0], s[ji], 0, 0, 0);
          s[ji] = __builtin_amdgcn_mfma_f32_16x16x32_bf16(kf[ji][1], qf[hh][ii][1], s[ji], 0, 0, 0);
        }
        const int i = ii * 16 + li;
        const int swzI = (i & 7) << 3;
#pragma unroll
        for (int ji = 0; ji < 4; ji++) {
          const float p0 = fexp2(s[ji][0] - stMp[hh][ii]);
          const float p1 = fexp2(s[ji][1] - stMp[hh][ii]);
          const float p2 = fexp2(s[ji][2] - stMp[hh][ii]);
          const float p3 = fexp2(s[ji][3] - stMp[hh][ii]);
          const int x = (ji * 16 + lg * 4) ^ swzI;
          *(uint2*)&Spk[i * SPK_STRIDE + h * 64 + x] = make_uint2(cvtpk(p0, p1), cvtpk(p2, p3));
        }
      }
    }
    __syncthreads();   // barrier1: Spk ready
    // MIX + LN: thread handles i = mixI, j = jt + mixJ8 + 0..7
    {
      uint4 sv[8];
#pragma unroll
      for (int h = 0; h < 8; h++)
        sv[h] = *(const uint4*)&Spk[mixI * SPK_STRIDE + h * 64 + (mixJ8 ^ mixSwz)];
      u32 ogw[8][4];
      float tmp[8];
#pragma unroll
      for (int hf = 0; hf < 2; hf++) {
        float p[8][4];
#pragma unroll
        for (int h = 0; h < 8; h++) {
          const u32 va = hf ? sv[h].z : sv[h].x;
          const u32 vb = hf ? sv[h].w : sv[h].y;
          union { u32 u; float f; } c0, c1, c2, c3;
          c0.u = va << 16; c1.u = va & 0xffff0000u;
          c2.u = vb << 16; c3.u = vb & 0xffff0000u;
          p[h][0] = c0.f; p[h][1] = c1.f; p[h][2] = c2.f; p[h][3] = c3.f;
        }
#pragma unroll
        for (int e = 0; e < 4; e++) {
          float a_[8]; float sum = 0.f, sumsq = 0.f;
#pragma unroll
          for (int g = 0; g < 8; g++) {
            float acc = 0.f;
#pragma unroll
            for (int h = 0; h < 8; h++) acc = fmaf(p[h][e], wm_[h][g], acc);
            a_[g] = acc; sum += acc; sumsq = fmaf(acc, acc, sumsq);
          }
          const float mu = sum * 0.125f;
          const float var = fmaf(sumsq, 0.125f, -mu * mu);
          const float rs = rsqrtf(var + 1e-5f);
#pragma unroll
          for (int g = 0; g < 8; g++) {
            const float av = fmaf((a_[g] - mu) * rs, lng_[g], lnb_[g]);
            if (e & 1) ogw[g][hf * 2 + (e >> 1)] = cvtpk(tmp[g], av);
            else       tmp[g] = av;
          }
        }
      }
#pragma unroll
      for (int g = 0; g < 8; g++)
        *(uint4*)&A2h[g * 2304 + mixI * 72 + (mixJ8 ^ mixSwz)] =
            make_uint4(ogw[g][0], ogw[g][1], ogw[g][2], ogw[g][3]);
    }
    __syncthreads();   // barrier2: A2h ready
    // PV per head; V loaded here (latency absorbed by sibling block's overlap)
    __builtin_amdgcn_s_setprio(1);
#pragma unroll
    for (int hh = 0; hh < 2; hh++) {
      const int h = w + hh * 4;
      bfx8 vf[2][4];
#pragma unroll
      for (int ks = 0; ks < 2; ks++)
#pragma unroll
        for (int dt = 0; dt < 4; dt++)
          vf[ks][dt] = *(const bfx8*)&vtb[(((size_t)(b * 8 + h)) * 64 + dt * 16 + li) * 2048
                                          + jt + ks * 32 + lg * 8];
      __builtin_amdgcn_sched_barrier(0);
#pragma unroll
      for (int iSub = 0; iSub < 2; iSub++) {
#pragma unroll
        for (int ks = 0; ks < 2; ks++) {
          const bfx8 af = *(const bfx8*)&A2h[h * 2304 + (iSub * 16 + li) * 72
                                             + ((ks * 32 + lg * 8) ^ ((li & 7) << 3))];
#pragma unroll
          for (int dt = 0; dt < 4; dt++)
            pacc[hh][iSub][dt] =
                __builtin_amdgcn_mfma_f32_16x16x32_bf16(af, vf[ks][dt], pacc[hh][iSub][dt], 0, 0, 0);
        }
      }
    }
    __builtin_amdgcn_s_setprio(0);
    // no trailing barrier: PV reads A2h; next QK^T writes Spk (disjoint);
    // mix(t+1)'s A2h writes are fenced by barrier1(t+1).
  }
  // epilogue: f32 atomic partials (4 jq contributions per element)
#pragma unroll
  for (int hh = 0; hh < 2; hh++)
#pragma unroll
    for (int iSub = 0; iSub < 2; iSub++)
#pragma unroll
      for (int dt = 0; dt < 4; dt++)
#pragma unroll
        for (int r = 0; r < 4; r++)
          atomicAdd(&innerF[((size_t)b * 2048 + ig + iSub * 16 + lg * 4 + r) * 512
                            + (w + hh * 4) * 64 + dt * 16 + li],
                    pacc[hh][iSub][dt][r]);
}

// ---------------- k4: out = innerF(f32) @ w_out^T + b_out, BM=64 ----------------
__global__ __launch_bounds__(256) void gemm_out(
    const float* __restrict__ A, const float* __restrict__ B,
    float* __restrict__ outf, const float* __restrict__ bias) {
  __shared__ u16 As[64 * 32];
  __shared__ u16 Bs[128 * 32];
  const int bid = blockIdx.x;
  const int swzb = (bid & 7) * 32 + (bid >> 3);
  const int m0 = (swzb >> 2) * 64, n0 = (swzb & 3) * 128;
  const int t = threadIdx.x, lane = t & 63, w = t >> 6;
  const int li = lane & 15, lg = lane >> 4;
  const int rowA = t >> 2, kb8 = (t & 3) * 8;
  f32x4 acc[4][2] = {};
  for (int k0 = 0; k0 < 512; k0 += 32) {
    __syncthreads();
    *(uint4*)&As[rowA * 32 + kb8]        = pk8(&A[(size_t)(m0 + rowA) * 512 + k0 + kb8]);
    *(uint4*)&Bs[rowA * 32 + kb8]        = pk8(&B[(size_t)(n0 + rowA) * 512 + k0 + kb8]);
    *(uint4*)&Bs[(rowA + 64) * 32 + kb8] = pk8(&B[(size_t)(n0 + rowA + 64) * 512 + k0 + kb8]);
    __syncthreads();
    bfx8 af[4], bf_[2];
#pragma unroll
    for (int mi = 0; mi < 4; mi++)
      af[mi] = *(const bfx8*)&As[(mi * 16 + li) * 32 + lg * 8];
#pragma unroll
    for (int ni = 0; ni < 2; ni++)
      bf_[ni] = *(const bfx8*)&Bs[(w * 32 + ni * 16 + li) * 32 + lg * 8];
#pragma unroll
    for (int mi = 0; mi < 4; mi++)
#pragma unroll
      for (int ni = 0; ni < 2; ni++)
        acc[mi][ni] = __builtin_amdgcn_mfma_f32_16x16x32_bf16(af[mi], bf_[ni], acc[mi][ni], 0, 0, 0);
  }
#pragma unroll
  for (int mi = 0; mi < 4; mi++) {
#pragma unroll
    for (int ni = 0; ni < 2; ni++) {
      const int nc  = n0 + w * 32 + ni * 16 + li;
      const int mrb = m0 + mi * 16 + lg * 4;
      const float bv = bias[nc];
#pragma unroll
      for (int r = 0; r < 4; r++)
        outf[(size_t)(mrb + r) * 512 + nc] = acc[mi][ni][r] + bv;
    }
  }
}

// ---------------- host ----------------
extern "C" void kernel_launch(void* const* d_in, const int* in_sizes, int n_in,
                              void* d_out, int out_size, void* d_ws, size_t ws_size,
                              hipStream_t stream) {
  const float* x      = (const float*)d_in[0];
  const float* w_qkv  = (const float*)d_in[1];
  const float* reattn = (const float*)d_in[2];
  const float* ln_g   = (const float*)d_in[3];
  const float* ln_b   = (const float*)d_in[4];
  const float* w_out  = (const float*)d_in[5];
  const float* b_out  = (const float*)d_in[6];
  float* out = (float*)d_out;
  char* ws = (char*)d_ws;
  // ws layout (bytes), ~23.1 MB:
  //  [0, 8388608)         innerF f32 (zeroed inside gemm_qkv)
  //  [8388608, 12582912)  qbf [2,8,2048,64] bf16 (scaled)
  //  [12582912,16777216)  kbf
  //  [16777216,20971520)  vtb [2,8,64,2048]
  //  [20971520,23068672)  statp [8][2,8,2048] float2
  float*  innerF= (float*)(ws + 0);
  u16*    qbf   = (u16*)(ws + 8388608);
  u16*    kbf   = (u16*)(ws + 12582912);
  u16*    vtb   = (u16*)(ws + 16777216);
  float2* statp = (float2*)(ws + 20971520);

  gemm_qkv<<<768, 256, 0, stream>>>(x, w_qkv, qbf, kbf, vtb, (float4*)innerF);
  passA<<<4096, 256, 0, stream>>>(qbf, kbf, statp);
  kFused<<<dim3(64, 2, 4), 256, 0, stream>>>(qbf, kbf, vtb, statp, reattn, ln_g, ln_b, innerF);
  gemm_out<<<256, 256, 0, stream>>>(innerF, w_out, out, b_out);
}

// Round 22
// 185.478 us; speedup vs baseline: 1.0234x; 1.0234x over previous
//
#include <hip/hip_runtime.h>
#include <hip/hip_bf16.h>

// DeepViT re-attention — fused S-in-LDS pipeline, v4-final (best config, R18/R20).
//  k1 gemm_qkv: qkv = x @ w_qkv^T, BM=64 (768 blocks = 3/CU), f32 stage-convert,
//               XCD swizzle, fused innerF zeroing
//  k2 passA   : softmax stats (m, l), j-split x8 (4096 blocks), XCD swizzle
//  k3 kFused  : grid dim3(32,2,4) — z=jq OUTERMOST so the 4 jq groups (which
//               contend on the same innerF atomics) stay on one XCD / time-
//               separated (R19: clustering them costs +7us in atomic ping-pong).
//               Per 64-j tile: QK^T 64x64/head in regs -> p bf16 -> Spk (LDS);
//               mix+LN pointwise -> A2h; PV. 2 barriers/tile; T14 V(t)+K(t+1)
//               prefetch issued after barrier1, drains at barrier2 under mix.
//  k4 gemm_out: out = innerF(f32 staged) @ w_out^T + b_out, BM=64 (256 blocks)

typedef __attribute__((ext_vector_type(8))) short bfx8;
typedef __attribute__((ext_vector_type(4))) float f32x4;
typedef unsigned short u16;
typedef unsigned int u32;

#define QSCALE 0.18033688011112042f  /* (1/8) * log2(e) */

static __device__ inline u16 f2bf(float f) {
  union { float f; unsigned u; } cv; cv.f = f;
  unsigned u = cv.u;
  u += 0x7fffu + ((u >> 16) & 1u);   // RNE
  return (u16)(u >> 16);
}
static __device__ inline u32 cvtpk(float lo, float hi) {  // {bf16(lo), bf16(hi)}
  u32 d; asm("v_cvt_pk_bf16_f32 %0, %1, %2" : "=v"(d) : "v"(lo), "v"(hi)); return d;
}
static __device__ inline float fexp2(float x) {
  float r; asm("v_exp_f32 %0, %1" : "=v"(r) : "v"(x)); return r;
}
static __device__ inline float flog2(float x) {
  float r; asm("v_log_f32 %0, %1" : "=v"(r) : "v"(x)); return r;
}
static __device__ inline uint4 pk8(const float* p) {  // 8 f32 -> 8 bf16 (uint4)
  float4 a = *(const float4*)p, b = *(const float4*)(p + 4);
  return make_uint4(cvtpk(a.x, a.y), cvtpk(a.z, a.w), cvtpk(b.x, b.y), cvtpk(b.z, b.w));
}

// ---------------- k1: GEMM C = x @ w_qkv^T, BM=64, fused innerF zero ----------------
__global__ __launch_bounds__(256) void gemm_qkv(
    const float* __restrict__ A, const float* __restrict__ B,
    u16* __restrict__ qb, u16* __restrict__ kb, u16* __restrict__ vtb,
    float4* __restrict__ zeroF) {
  __shared__ u16 As[64 * 32];
  __shared__ u16 Bs[128 * 32];
  const int bid = blockIdx.x, t = threadIdx.x;
  for (int e = bid * 256 + t; e < 524288; e += 196608)
    zeroF[e] = make_float4(0.f, 0.f, 0.f, 0.f);
  const int swzb = (bid & 7) * 96 + (bid >> 3);
  const int m0 = (swzb / 12) * 64, n0 = (swzb % 12) * 128;
  const int lane = t & 63, w = t >> 6;
  const int li = lane & 15, lg = lane >> 4;
  const int rowA = t >> 2, kb8 = (t & 3) * 8;
  f32x4 acc[4][2] = {};
  for (int k0 = 0; k0 < 512; k0 += 32) {
    __syncthreads();
    *(uint4*)&As[rowA * 32 + kb8]        = pk8(&A[(size_t)(m0 + rowA) * 512 + k0 + kb8]);
    *(uint4*)&Bs[rowA * 32 + kb8]        = pk8(&B[(size_t)(n0 + rowA) * 512 + k0 + kb8]);
    *(uint4*)&Bs[(rowA + 64) * 32 + kb8] = pk8(&B[(size_t)(n0 + rowA + 64) * 512 + k0 + kb8]);
    __syncthreads();
    bfx8 af[4], bf_[2];
#pragma unroll
    for (int mi = 0; mi < 4; mi++)
      af[mi] = *(const bfx8*)&As[(mi * 16 + li) * 32 + lg * 8];
#pragma unroll
    for (int ni = 0; ni < 2; ni++)
      bf_[ni] = *(const bfx8*)&Bs[(w * 32 + ni * 16 + li) * 32 + lg * 8];
#pragma unroll
    for (int mi = 0; mi < 4; mi++)
#pragma unroll
      for (int ni = 0; ni < 2; ni++)
        acc[mi][ni] = __builtin_amdgcn_mfma_f32_16x16x32_bf16(af[mi], bf_[ni], acc[mi][ni], 0, 0, 0);
  }
#pragma unroll
  for (int mi = 0; mi < 4; mi++) {
#pragma unroll
    for (int ni = 0; ni < 2; ni++) {
      const int nc  = n0 + w * 32 + ni * 16 + li;
      const int mrb = m0 + mi * 16 + lg * 4;
      const int part = nc >> 9, within = nc & 511;
      const int h = within >> 6, d = within & 63;
      const int bb = mrb >> 11, ii = mrb & 2047;
      if (part == 0) {
#pragma unroll
        for (int r = 0; r < 4; r++)
          qb[(((size_t)bb * 8 + h) * 2048 + ii + r) * 64 + d] = f2bf(acc[mi][ni][r] * QSCALE);
      } else if (part == 1) {
#pragma unroll
        for (int r = 0; r < 4; r++)
          kb[(((size_t)bb * 8 + h) * 2048 + ii + r) * 64 + d] = f2bf(acc[mi][ni][r]);
      } else {
        ushort4 u;
        u.x = f2bf(acc[mi][ni][0]); u.y = f2bf(acc[mi][ni][1]);
        u.z = f2bf(acc[mi][ni][2]); u.w = f2bf(acc[mi][ni][3]);
        *(ushort4*)&vtb[(((size_t)bb * 8 + h) * 64 + d) * 2048 + ii] = u;
      }
    }
  }
}

// ---------------- k2: softmax stats (m, l), j-split x8, XCD-swizzled ----------------
__global__ __launch_bounds__(256) void passA(
    const u16* __restrict__ qb, const u16* __restrict__ kb,
    float2* __restrict__ statp) {
  const int bid = blockIdx.x;
  const int swzb = (bid & 7) * 512 + (bid >> 3);
  const int bx = swzb & 31, bh = (swzb >> 5) & 15, js = swzb >> 9;  // js 0..7
  const int t = threadIdx.x, lane = t & 63, w = t >> 6;
  const int i0 = bx * 64 + w * 16;
  const int li = lane & 15, lg = lane >> 4;
  const u16* Qh = qb + ((size_t)bh * 2048 + i0 + li) * 64;
  const u16* Kb = kb + (size_t)bh * 2048 * 64;
  const bfx8 q0 = *(const bfx8*)&Qh[lg * 8];
  const bfx8 q1 = *(const bfx8*)&Qh[32 + lg * 8];
  float m = -1e30f, l = 0.f;
  const int jbeg = js * 256, jend = jbeg + 256;
  for (int j0 = jbeg; j0 < jend; j0 += 32) {
    const u16* KhA = Kb + (size_t)(j0 + li) * 64;
    const u16* KhB = KhA + 16 * 64;
    bfx8 a0 = *(const bfx8*)&KhA[lg * 8];
    bfx8 a1 = *(const bfx8*)&KhA[32 + lg * 8];
    bfx8 b0 = *(const bfx8*)&KhB[lg * 8];
    bfx8 b1 = *(const bfx8*)&KhB[32 + lg * 8];
    __builtin_amdgcn_sched_barrier(0);
    f32x4 sa = {0.f, 0.f, 0.f, 0.f}, sb = {0.f, 0.f, 0.f, 0.f};
    sa = __builtin_amdgcn_mfma_f32_16x16x32_bf16(a0, q0, sa, 0, 0, 0);
    sa = __builtin_amdgcn_mfma_f32_16x16x32_bf16(a1, q1, sa, 0, 0, 0);
    sb = __builtin_amdgcn_mfma_f32_16x16x32_bf16(b0, q0, sb, 0, 0, 0);
    sb = __builtin_amdgcn_mfma_f32_16x16x32_bf16(b1, q1, sb, 0, 0, 0);
    float mt = fmaxf(fmaxf(fmaxf(sa[0], sa[1]), fmaxf(sa[2], sa[3])),
                     fmaxf(fmaxf(sb[0], sb[1]), fmaxf(sb[2], sb[3])));
    float mn = fmaxf(m, mt);
    float es = (fexp2(sa[0] - mn) + fexp2(sa[1] - mn)) + (fexp2(sa[2] - mn) + fexp2(sa[3] - mn))
             + (fexp2(sb[0] - mn) + fexp2(sb[1] - mn)) + (fexp2(sb[2] - mn) + fexp2(sb[3] - mn));
    l = fmaf(l, fexp2(m - mn), es);
    m = mn;
  }
  for (int off = 16; off < 64; off <<= 1) {
    float mo = __shfl_xor(m, off, 64);
    float lo = __shfl_xor(l, off, 64);
    float mn = fmaxf(m, mo);
    l = l * fexp2(m - mn) + lo * fexp2(mo - mn);
    m = mn;
  }
  if (lane < 16) statp[(size_t)js * 32768 + (size_t)bh * 2048 + i0 + li] = make_float2(m, l);
}

// ---------------- k3: kFused — QK^T + softmax + mix + LN + PV, S in LDS ----------------
// grid (32 i-tiles of 64, 2 b, 4 j-quarters), 512 thr = 8 waves, wave = head.
__global__ __launch_bounds__(512) void kFused(
    const u16* __restrict__ qb, const u16* __restrict__ kb,
    const u16* __restrict__ vtb, const float2* __restrict__ statp,
    const float* __restrict__ Wmix, const float* __restrict__ lng,
    const float* __restrict__ lnb, float* __restrict__ innerF) {
  __shared__ __align__(16) u16 Spk[64 * 512];     // 64KB  p bf16 [i][h][x]
  __shared__ __align__(16) u16 A2h[8 * 64 * 72];  // 72KB  A'' bf16 [g][i][x]
  __shared__ float stMs[64 * 8];                  // 2KB   M = m+log2(l) [i][h]
  const int t = threadIdx.x, lane = t & 63, w = t >> 6;
  const int li = lane & 15, lg = lane >> 4;
  const int ig = blockIdx.x * 64, b = blockIdx.y, j0 = blockIdx.z * 512;

  float wm_[8][8], lng_[8], lnb_[8];   // uniform -> SGPR
#pragma unroll
  for (int h = 0; h < 8; h++)
#pragma unroll
    for (int g = 0; g < 8; g++) wm_[h][g] = Wmix[h * 8 + g];
#pragma unroll
  for (int g = 0; g < 8; g++) { lng_[g] = lng[g]; lnb_[g] = lnb[g]; }

  // stats merge over 8 j-split partials -> stMs[i][h]
  {
    const int i = t >> 3, h = t & 7;
    const size_t idx = ((size_t)(b * 8 + h)) * 2048 + ig + i;
    float m = -1e30f, l = 0.f;
#pragma unroll
    for (int z = 0; z < 8; z++) {
      const float2 a = statp[(size_t)z * 32768 + idx];
      const float mn = fmaxf(m, a.x);
      l = l * fexp2(m - mn) + a.y * fexp2(a.x - mn);
      m = mn;
    }
    stMs[i * 8 + h] = m + flog2(l);
  }

  // Q fragments for head w (held in regs for the whole block)
  bfx8 qf[4][2];
#pragma unroll
  for (int ii = 0; ii < 4; ii++)
#pragma unroll
    for (int ks = 0; ks < 2; ks++)
      qf[ii][ks] = *(const bfx8*)&qb[(((size_t)(b * 8 + w)) * 2048 + ig + ii * 16 + li) * 64
                                     + ks * 32 + lg * 8];
  __syncthreads();
  float stMp[4];
#pragma unroll
  for (int ii = 0; ii < 4; ii++) stMp[ii] = stMs[(ii * 16 + li) * 8 + w];

  f32x4 pacc[4][4] = {};
  const int mixI = t >> 3, mixJ8 = (t & 7) * 8;   // mix-phase position base
  const int mixSwz = (mixI & 7) << 3;

  // K prologue: fragments for tile 0
  bfx8 kf[4][2];
#pragma unroll
  for (int ji = 0; ji < 4; ji++)
#pragma unroll
    for (int ks = 0; ks < 2; ks++)
      kf[ji][ks] = *(const bfx8*)&kb[(((size_t)(b * 8 + w)) * 2048 + j0 + ji * 16 + li) * 64
                                     + ks * 32 + lg * 8];

  for (int jt = j0; jt < j0 + 512; jt += 64) {
    // QK^T + exp + pack to Spk. element: j = jt + ji*16 + lg*4 + r, i = ii*16 + li.
#pragma unroll
    for (int ii = 0; ii < 4; ii++) {
      f32x4 s[4] = {};
#pragma unroll
      for (int ji = 0; ji < 4; ji++) {
        s[ji] = __builtin_amdgcn_mfma_f32_16x16x32_bf16(kf[ji][0], qf[ii][0], s[ji], 0, 0, 0);
        s[ji] = __builtin_amdgcn_mfma_f32_16x16x32_bf16(kf[ji][1], qf[ii][1], s[ji], 0, 0, 0);
      }
      const int i = ii * 16 + li;
      const int swzI = (i & 7) << 3;
#pragma unroll
      for (int ji = 0; ji < 4; ji++) {
        const float p0 = fexp2(s[ji][0] - stMp[ii]);
        const float p1 = fexp2(s[ji][1] - stMp[ii]);
        const float p2 = fexp2(s[ji][2] - stMp[ii]);
        const float p3 = fexp2(s[ji][3] - stMp[ii]);
        const int x = (ji * 16 + lg * 4) ^ swzI;
        *(uint2*)&Spk[i * 512 + w * 64 + x] = make_uint2(cvtpk(p0, p1), cvtpk(p2, p3));
      }
    }
    __syncthreads();   // barrier1: Spk ready
    // T14: V(current) + K(next) issued here -> drained at barrier2 (hidden by mix)
    bfx8 vf0[4], vf1[4];
#pragma unroll
    for (int dt = 0; dt < 4; dt++) {
      vf0[dt] = *(const bfx8*)&vtb[(((size_t)(b * 8 + w)) * 64 + dt * 16 + li) * 2048
                                   + jt + lg * 8];
      vf1[dt] = *(const bfx8*)&vtb[(((size_t)(b * 8 + w)) * 64 + dt * 16 + li) * 2048
                                   + jt + 32 + lg * 8];
    }
    {
      const int jn = (jt + 64 < j0 + 512) ? jt + 64 : j0;
#pragma unroll
      for (int ji = 0; ji < 4; ji++)
#pragma unroll
        for (int ks = 0; ks < 2; ks++)
          kf[ji][ks] = *(const bfx8*)&kb[(((size_t)(b * 8 + w)) * 2048 + jn + ji * 16 + li) * 64
                                         + ks * 32 + lg * 8];
    }
    __builtin_amdgcn_sched_barrier(0);
    // MIX + LN: thread handles 8 positions (i = mixI, j = jt + mixJ8 + 0..7)
    {
      uint4 sv[8];
#pragma unroll
      for (int h = 0; h < 8; h++)
        sv[h] = *(const uint4*)&Spk[mixI * 512 + h * 64 + (mixJ8 ^ mixSwz)];
      u32 ogw[8][4];
      float tmp[8];
#pragma unroll
      for (int hf = 0; hf < 2; hf++) {
        float p[8][4];
#pragma unroll
        for (int h = 0; h < 8; h++) {
          const u32 va = hf ? sv[h].z : sv[h].x;
          const u32 vb = hf ? sv[h].w : sv[h].y;
          union { u32 u; float f; } c0, c1, c2, c3;
          c0.u = va << 16; c1.u = va & 0xffff0000u;
          c2.u = vb << 16; c3.u = vb & 0xffff0000u;
          p[h][0] = c0.f; p[h][1] = c1.f; p[h][2] = c2.f; p[h][3] = c3.f;
        }
#pragma unroll
        for (int e = 0; e < 4; e++) {
          float a_[8]; float sum = 0.f, sumsq = 0.f;
#pragma unroll
          for (int g = 0; g < 8; g++) {
            float acc = 0.f;
#pragma unroll
            for (int h = 0; h < 8; h++) acc = fmaf(p[h][e], wm_[h][g], acc);
            a_[g] = acc; sum += acc; sumsq = fmaf(acc, acc, sumsq);
          }
          const float mu = sum * 0.125f;
          const float var = fmaf(sumsq, 0.125f, -mu * mu);
          const float rs = rsqrtf(var + 1e-5f);
#pragma unroll
          for (int g = 0; g < 8; g++) {
            const float av = fmaf((a_[g] - mu) * rs, lng_[g], lnb_[g]);
            if (e & 1) ogw[g][hf * 2 + (e >> 1)] = cvtpk(tmp[g], av);
            else       tmp[g] = av;
          }
        }
      }
#pragma unroll
      for (int g = 0; g < 8; g++)
        *(uint4*)&A2h[g * 4608 + mixI * 72 + (mixJ8 ^ mixSwz)] =
            make_uint4(ogw[g][0], ogw[g][1], ogw[g][2], ogw[g][3]);
    }
    __syncthreads();   // barrier2: A2h ready; V/K prefetch drains here
    // PV: head w; A = A''[i][j] from A2h, B = V (prefetched under mix).
    // No trailing barrier — PV reads A2h; next QK^T writes Spk (disjoint);
    // mix(t+1)'s A2h writes are fenced by barrier1(t+1).
    __builtin_amdgcn_s_setprio(1);
#pragma unroll
    for (int iSub = 0; iSub < 4; iSub++) {
      const bfx8 af0 = *(const bfx8*)&A2h[w * 4608 + (iSub * 16 + li) * 72
                                          + ((lg * 8) ^ ((li & 7) << 3))];
#pragma unroll
      for (int dt = 0; dt < 4; dt++)
        pacc[iSub][dt] = __builtin_amdgcn_mfma_f32_16x16x32_bf16(af0, vf0[dt], pacc[iSub][dt], 0, 0, 0);
    }
#pragma unroll
    for (int iSub = 0; iSub < 4; iSub++) {
      const bfx8 af1 = *(const bfx8*)&A2h[w * 4608 + (iSub * 16 + li) * 72
                                          + ((32 + lg * 8) ^ ((li & 7) << 3))];
#pragma unroll
      for (int dt = 0; dt < 4; dt++)
        pacc[iSub][dt] = __builtin_amdgcn_mfma_f32_16x16x32_bf16(af1, vf1[dt], pacc[iSub][dt], 0, 0, 0);
    }
    __builtin_amdgcn_s_setprio(0);
  }
  // epilogue: f32 atomic partials (4 j-quarter contributions per element)
#pragma unroll
  for (int iSub = 0; iSub < 4; iSub++)
#pragma unroll
    for (int dt = 0; dt < 4; dt++)
#pragma unroll
      for (int r = 0; r < 4; r++)
        atomicAdd(&innerF[((size_t)b * 2048 + ig + iSub * 16 + lg * 4 + r) * 512
                          + w * 64 + dt * 16 + li],
                  pacc[iSub][dt][r]);
}

// ---------------- k4: out = innerF(f32) @ w_out^T + b_out, BM=64 ----------------
__global__ __launch_bounds__(256) void gemm_out(
    const float* __restrict__ A, const float* __restrict__ B,
    float* __restrict__ outf, const float* __restrict__ bias) {
  __shared__ u16 As[64 * 32];
  __shared__ u16 Bs[128 * 32];
  const int bid = blockIdx.x;
  const int swzb = (bid & 7) * 32 + (bid >> 3);
  const int m0 = (swzb >> 2) * 64, n0 = (swzb & 3) * 128;
  const int t = threadIdx.x, lane = t & 63, w = t >> 6;
  const int li = lane & 15, lg = lane >> 4;
  const int rowA = t >> 2, kb8 = (t & 3) * 8;
  f32x4 acc[4][2] = {};
  for (int k0 = 0; k0 < 512; k0 += 32) {
    __syncthreads();
    *(uint4*)&As[rowA * 32 + kb8]        = pk8(&A[(size_t)(m0 + rowA) * 512 + k0 + kb8]);
    *(uint4*)&Bs[rowA * 32 + kb8]        = pk8(&B[(size_t)(n0 + rowA) * 512 + k0 + kb8]);
    *(uint4*)&Bs[(rowA + 64) * 32 + kb8] = pk8(&B[(size_t)(n0 + rowA + 64) * 512 + k0 + kb8]);
    __syncthreads();
    bfx8 af[4], bf_[2];
#pragma unroll
    for (int mi = 0; mi < 4; mi++)
      af[mi] = *(const bfx8*)&As[(mi * 16 + li) * 32 + lg * 8];
#pragma unroll
    for (int ni = 0; ni < 2; ni++)
      bf_[ni] = *(const bfx8*)&Bs[(w * 32 + ni * 16 + li) * 32 + lg * 8];
#pragma unroll
    for (int mi = 0; mi < 4; mi++)
#pragma unroll
      for (int ni = 0; ni < 2; ni++)
        acc[mi][ni] = __builtin_amdgcn_mfma_f32_16x16x32_bf16(af[mi], bf_[ni], acc[mi][ni], 0, 0, 0);
  }
#pragma unroll
  for (int mi = 0; mi < 4; mi++) {
#pragma unroll
    for (int ni = 0; ni < 2; ni++) {
      const int nc  = n0 + w * 32 + ni * 16 + li;
      const int mrb = m0 + mi * 16 + lg * 4;
      const float bv = bias[nc];
#pragma unroll
      for (int r = 0; r < 4; r++)
        outf[(size_t)(mrb + r) * 512 + nc] = acc[mi][ni][r] + bv;
    }
  }
}

// ---------------- host ----------------
extern "C" void kernel_launch(void* const* d_in, const int* in_sizes, int n_in,
                              void* d_out, int out_size, void* d_ws, size_t ws_size,
                              hipStream_t stream) {
  const float* x      = (const float*)d_in[0];
  const float* w_qkv  = (const float*)d_in[1];
  const float* reattn = (const float*)d_in[2];
  const float* ln_g   = (const float*)d_in[3];
  const float* ln_b   = (const float*)d_in[4];
  const float* w_out  = (const float*)d_in[5];
  const float* b_out  = (const float*)d_in[6];
  float* out = (float*)d_out;
  char* ws = (char*)d_ws;
  // ws layout (bytes), ~23.1 MB:
  //  [0, 8388608)         innerF f32 (zeroed inside gemm_qkv)
  //  [8388608, 12582912)  qbf [2,8,2048,64] bf16 (scaled)
  //  [12582912,16777216)  kbf
  //  [16777216,20971520)  vtb [2,8,64,2048]
  //  [20971520,23068672)  statp [8][2,8,2048] float2
  float*  innerF= (float*)(ws + 0);
  u16*    qbf   = (u16*)(ws + 8388608);
  u16*    kbf   = (u16*)(ws + 12582912);
  u16*    vtb   = (u16*)(ws + 16777216);
  float2* statp = (float2*)(ws + 20971520);

  gemm_qkv<<<768, 256, 0, stream>>>(x, w_qkv, qbf, kbf, vtb, (float4*)innerF);
  passA<<<4096, 256, 0, stream>>>(qbf, kbf, statp);
  kFused<<<dim3(32, 2, 4), 512, 0, stream>>>(qbf, kbf, vtb, statp, reattn, ln_g, ln_b, innerF);
  gemm_out<<<256, 256, 0, stream>>>(innerF, w_out, out, b_out);
}